// Round 1
// baseline (267.425 us; speedup 1.0000x reference)
//
#include <hip/hip_runtime.h>
#include <hip/hip_bf16.h>
#include <math.h>

#define DIM   5120
#define NH    40
#define NKV   8
#define HD    128
#define BS    8
#define KLEN  4096
#define NEWT  4095
#define NREP  5

#define ODQKV 7168          // 5120 + 1024 + 1024 combined output columns
#define NKC   32            // split-K chunks for GEMVs
#define KCH   (DIM / NKC)   // 160 rows per chunk

#define NCHUNK 8            // t-chunks per (b,h)
#define CH_T   (KLEN / NCHUNK)  // 512
#define WAVE_T (CH_T / 4)       // 128 t per wave
#define NPART  (NCHUNK * 4)     // 32 partials per (b,h)

// workspace layout (in floats)
#define WS_Q       0
#define WS_K       (WS_Q + BS * DIM)        // 40960
#define WS_V       (WS_K + BS * NKV * HD)   // 49152
#define WS_ATTN    (WS_V + BS * NKV * HD)   // 57344
#define WS_SCRATCH (WS_ATTN + BS * DIM)     // 98304  (scratch reused across phases)

// ---------------------------------------------------------------------------
// Phase A: combined QKV GEMV, split-K partials.
// grid = 28 column-blocks * NKC k-chunks. Each thread owns one output column
// for all 8 batches; x chunk staged in LDS (wave-uniform broadcast reads).
// ---------------------------------------------------------------------------
__global__ __launch_bounds__(256) void qkv_partial_k(
    const float* __restrict__ x, const float* __restrict__ wq,
    const float* __restrict__ wk, const float* __restrict__ wv,
    float* __restrict__ part) {
  const int cb  = blockIdx.x % 28;
  const int kc  = blockIdx.x / 28;
  const int tid = threadIdx.x;
  const int c   = cb * 256 + tid;

  const float* w; int OD, j;
  if (c < 5120)      { w = wq; OD = 5120; j = c; }
  else if (c < 6144) { w = wk; OD = 1024; j = c - 5120; }
  else               { w = wv; OD = 1024; j = c - 6144; }

  __shared__ float xs[BS * KCH];
  const int i0 = kc * KCH;
  for (int idx = tid; idx < BS * KCH; idx += 256) {
    int b = idx / KCH, ii = idx - b * KCH;
    xs[idx] = x[b * DIM + i0 + ii];
  }
  __syncthreads();

  float acc[BS];
#pragma unroll
  for (int b = 0; b < BS; ++b) acc[b] = 0.f;

  const float* wp = w + (size_t)i0 * OD + j;
  for (int ii = 0; ii < KCH; ++ii) {
    float wval = wp[(size_t)ii * OD];
#pragma unroll
    for (int b = 0; b < BS; ++b) acc[b] = fmaf(xs[b * KCH + ii], wval, acc[b]);
  }
#pragma unroll
  for (int b = 0; b < BS; ++b)
    part[((size_t)kc * BS + b) * ODQKV + c] = acc[b];
}

// ---------------------------------------------------------------------------
// Phase A2: reduce partials, add bias, apply RoPE (pos 4095), fold 1/sqrt(128)
// into q. One thread per even/odd column pair per batch.
// ---------------------------------------------------------------------------
__global__ __launch_bounds__(256) void qkv_reduce_k(
    const float* __restrict__ part, const float* __restrict__ bq,
    const float* __restrict__ bk, const float* __restrict__ bv,
    const float* __restrict__ fc, float* __restrict__ qws,
    float* __restrict__ kws, float* __restrict__ vws) {
  int g = blockIdx.x * 256 + threadIdx.x;
  if (g >= BS * (ODQKV / 2)) return;
  int b  = g / (ODQKV / 2);
  int cp = g - b * (ODQKV / 2);
  int c0 = cp * 2;

  float sx = 0.f, sy = 0.f;
  for (int kc = 0; kc < NKC; ++kc) {
    const float2 p = *(const float2*)&part[((size_t)kc * BS + b) * ODQKV + c0];
    sx += p.x; sy += p.y;
  }

  const float scale = 0.088388347648318447f;  // 1/sqrt(128)
  if (c0 < 5120) {
    sx += bq[c0]; sy += bq[c0 + 1];
    int jf = (c0 & 127) >> 1;
    float cs = fc[2 * jf], sn = fc[2 * jf + 1];
    qws[b * DIM + c0]     = (sx * cs - sy * sn) * scale;
    qws[b * DIM + c0 + 1] = (sx * sn + sy * cs) * scale;
  } else if (c0 < 6144) {
    int jj = c0 - 5120;
    sx += bk[jj]; sy += bk[jj + 1];
    int jf = (jj & 127) >> 1;
    float cs = fc[2 * jf], sn = fc[2 * jf + 1];
    kws[b * NKV * HD + jj]     = sx * cs - sy * sn;
    kws[b * NKV * HD + jj + 1] = sx * sn + sy * cs;
  } else {
    int jj = c0 - 6144;
    vws[b * NKV * HD + jj]     = sx + bv[jj];
    vws[b * NKV * HD + jj + 1] = sy + bv[jj + 1];
  }
}

// ---------------------------------------------------------------------------
// Phase B: flash-decode partials. grid = 64 (b,h) * NCHUNK; 4 waves/block,
// each wave owns 128 consecutive t. float2/lane K,V rows; 5-head dot +
// butterfly reduce; online softmax with wave-uniform max-update branch.
// t == 4095 reads the freshly projected k/v (cache input is NOT mutated).
// ---------------------------------------------------------------------------
__global__ __launch_bounds__(256) void attn_partial_k(
    const float* __restrict__ ck, const float* __restrict__ cv,
    const float* __restrict__ qws, const float* __restrict__ kws,
    const float* __restrict__ vws, float* __restrict__ pM,
    float* __restrict__ pL, float* __restrict__ pO) {
  const int blk   = blockIdx.x;
  const int chunk = blk & (NCHUNK - 1);
  const int bh    = blk / NCHUNK;
  const int h     = bh & (NKV - 1);
  const int b     = bh / NKV;
  const int wave  = threadIdx.x >> 6;
  const int lane  = threadIdx.x & 63;
  const int widx  = chunk * 4 + wave;
  const int t0    = chunk * CH_T + wave * WAVE_T;

  float2 q[NREP];
#pragma unroll
  for (int r = 0; r < NREP; ++r)
    q[r] = *(const float2*)&qws[b * DIM + (h * NREP + r) * HD + 2 * lane];

  float m[NREP], l[NREP];
  float2 o[NREP];
#pragma unroll
  for (int r = 0; r < NREP; ++r) {
    m[r] = -1e30f; l[r] = 0.f; o[r] = make_float2(0.f, 0.f);
  }

  for (int t = t0; t < t0 + WAVE_T; ++t) {
    const float* kr = (t == NEWT) ? &kws[(b * NKV + h) * HD]
                                  : &ck[(((size_t)b * KLEN + t) * NKV + h) * HD];
    float2 kv = *(const float2*)&kr[2 * lane];
    float s[NREP];
#pragma unroll
    for (int r = 0; r < NREP; ++r) s[r] = q[r].x * kv.x + q[r].y * kv.y;
#pragma unroll
    for (int off = 32; off > 0; off >>= 1) {
#pragma unroll
      for (int r = 0; r < NREP; ++r) s[r] += __shfl_xor(s[r], off, 64);
    }
    const float* vr = (t == NEWT) ? &vws[(b * NKV + h) * HD]
                                  : &cv[(((size_t)b * KLEN + t) * NKV + h) * HD];
    float2 vv = *(const float2*)&vr[2 * lane];
#pragma unroll
    for (int r = 0; r < NREP; ++r) {
      if (s[r] <= m[r]) {               // wave-uniform branch (s is uniform)
        float p = __expf(s[r] - m[r]);
        l[r] += p;
        o[r].x += p * vv.x; o[r].y += p * vv.y;
      } else {
        float rs = __expf(m[r] - s[r]);
        l[r] = l[r] * rs + 1.f;
        o[r].x = o[r].x * rs + vv.x;
        o[r].y = o[r].y * rs + vv.y;
        m[r] = s[r];
      }
    }
  }

  const int pb = bh * NPART + widx;
  if (lane == 0) {
#pragma unroll
    for (int r = 0; r < NREP; ++r) {
      pM[pb * NREP + r] = m[r];
      pL[pb * NREP + r] = l[r];
    }
  }
#pragma unroll
  for (int r = 0; r < NREP; ++r)
    *(float2*)&pO[((size_t)pb * NREP + r) * HD + 2 * lane] = o[r];
}

// ---------------------------------------------------------------------------
// Phase B2: combine 32 partials per (b,h) with exp rescale; write attn rows.
// ---------------------------------------------------------------------------
__global__ __launch_bounds__(256) void attn_combine_k(
    const float* __restrict__ pM, const float* __restrict__ pL,
    const float* __restrict__ pO, float* __restrict__ attn) {
  const int bh  = blockIdx.x;
  const int h   = bh & (NKV - 1);
  const int b   = bh / NKV;
  const int tid = threadIdx.x;
  __shared__ float ml[NREP * NPART], ll[NREP * NPART];
  __shared__ float wgt[NREP * NPART];
  __shared__ float Linv[NREP];

  if (tid < NREP * NPART) {
    int r = tid / NPART, w = tid - r * NPART;
    ml[tid] = pM[(bh * NPART + w) * NREP + r];
    ll[tid] = pL[(bh * NPART + w) * NREP + r];
  }
  __syncthreads();
  if (tid < NREP * NPART) {
    int r = tid / NPART;
    float M = -1e30f;
    for (int w = 0; w < NPART; ++w) M = fmaxf(M, ml[r * NPART + w]);
    float e = __expf(ml[tid] - M);
    wgt[tid] = e;
    ll[tid] *= e;
  }
  __syncthreads();
  if (tid < NREP) {
    float L = 0.f;
    for (int w = 0; w < NPART; ++w) L += ll[tid * NPART + w];
    Linv[tid] = 1.f / L;
  }
  __syncthreads();

  for (int oidx = tid; oidx < NREP * HD; oidx += 256) {
    int r = oidx >> 7, d = oidx & 127;
    float acc = 0.f;
    for (int w = 0; w < NPART; ++w)
      acc += wgt[r * NPART + w] * pO[((size_t)(bh * NPART + w) * NREP + r) * HD + d];
    attn[b * DIM + (h * NREP + r) * HD + d] = acc * Linv[r];
  }
}

// ---------------------------------------------------------------------------
// Phase C: output projection GEMV (split-K) + reduce with bias.
// ---------------------------------------------------------------------------
__global__ __launch_bounds__(256) void out_partial_k(
    const float* __restrict__ attn, const float* __restrict__ wo,
    float* __restrict__ part) {
  const int cb  = blockIdx.x % 20;
  const int kc  = blockIdx.x / 20;
  const int tid = threadIdx.x;
  const int c   = cb * 256 + tid;

  __shared__ float xs[BS * KCH];
  const int i0 = kc * KCH;
  for (int idx = tid; idx < BS * KCH; idx += 256) {
    int b = idx / KCH, ii = idx - b * KCH;
    xs[idx] = attn[b * DIM + i0 + ii];
  }
  __syncthreads();

  float acc[BS];
#pragma unroll
  for (int b = 0; b < BS; ++b) acc[b] = 0.f;

  const float* wp = wo + (size_t)i0 * DIM + c;
  for (int ii = 0; ii < KCH; ++ii) {
    float wval = wp[(size_t)ii * DIM];
#pragma unroll
    for (int b = 0; b < BS; ++b) acc[b] = fmaf(xs[b * KCH + ii], wval, acc[b]);
  }
#pragma unroll
  for (int b = 0; b < BS; ++b)
    part[((size_t)kc * BS + b) * DIM + c] = acc[b];
}

__global__ __launch_bounds__(256) void out_reduce_k(
    const float* __restrict__ part, const float* __restrict__ bo,
    float* __restrict__ out) {
  int g = blockIdx.x * 256 + threadIdx.x;
  if (g >= BS * DIM) return;
  int b = g / DIM, c = g - b * DIM;
  float s = 0.f;
  for (int kc = 0; kc < NKC; ++kc) s += part[((size_t)kc * BS + b) * DIM + c];
  out[g] = s + bo[c];
}

// ---------------------------------------------------------------------------
extern "C" void kernel_launch(void* const* d_in, const int* in_sizes, int n_in,
                              void* d_out, int out_size, void* d_ws, size_t ws_size,
                              hipStream_t stream) {
  const float* x  = (const float*)d_in[0];
  // d_in[1] = start_pos (hardcoded 4095 per problem constants)
  const float* fc = (const float*)d_in[2];
  const float* ck = (const float*)d_in[3];
  const float* cv = (const float*)d_in[4];
  const float* wq = (const float*)d_in[5];
  const float* bq = (const float*)d_in[6];
  const float* wk = (const float*)d_in[7];
  const float* bk = (const float*)d_in[8];
  const float* wv = (const float*)d_in[9];
  const float* bv = (const float*)d_in[10];
  const float* wo = (const float*)d_in[11];
  const float* bo = (const float*)d_in[12];

  float* ws      = (float*)d_ws;
  float* qws     = ws + WS_Q;
  float* kws     = ws + WS_K;
  float* vws     = ws + WS_V;
  float* attn    = ws + WS_ATTN;
  float* scratch = ws + WS_SCRATCH;

  // Phase A: QKV projection
  qkv_partial_k<<<28 * NKC, 256, 0, stream>>>(x, wq, wk, wv, scratch);
  qkv_reduce_k<<<(BS * (ODQKV / 2) + 255) / 256, 256, 0, stream>>>(
      scratch, bq, bk, bv, fc, qws, kws, vws);

  // Phase B: attention (scratch reused for softmax partials)
  float* pM = scratch;
  float* pL = pM + 64 * NPART * NREP;
  float* pO = pL + 64 * NPART * NREP;
  attn_partial_k<<<64 * NCHUNK, 256, 0, stream>>>(ck, cv, qws, kws, vws, pM, pL, pO);
  attn_combine_k<<<64, 256, 0, stream>>>(pM, pL, pO, attn);

  // Phase C: output projection (scratch reused for GEMV partials)
  out_partial_k<<<20 * NKC, 256, 0, stream>>>(attn, wo, scratch);
  out_reduce_k<<<(BS * DIM + 255) / 256, 256, 0, stream>>>(scratch, bo, (float*)d_out);
}

// Round 4
// 193.409 us; speedup vs baseline: 1.3827x; 1.3827x over previous
//
#include <hip/hip_runtime.h>
#include <hip/hip_bf16.h>
#include <math.h>

#define DIM   5120
#define NH    40
#define NKV   8
#define HD    128
#define BS    8
#define KLEN  4096
#define NEWT  4095
#define NREP  5

#define ODQKV 7168          // 5120 + 1024 + 1024 combined output columns
#define NKC   32            // split-K chunks for GEMVs
#define KCH   (DIM / NKC)   // 160 rows per chunk

#define NCHUNK 16               // t-chunks per (b,h)
#define CH_T   (KLEN / NCHUNK)  // 256
#define WAVE_T (CH_T / 4)       // 64 t per wave
#define NPART  (NCHUNK * 4)     // 64 partials per (b,h)

// workspace layout (in floats)
#define WS_Q       0
#define WS_K       (WS_Q + BS * DIM)        // 40960
#define WS_V       (WS_K + BS * NKV * HD)   // 49152
#define WS_ATTN    (WS_V + BS * NKV * HD)   // 57344
#define WS_SCRATCH (WS_ATTN + BS * DIM)     // 98304  (scratch reused across phases)

// ---------------------------------------------------------------------------
// Phase A: combined QKV GEMV, split-K partials.
// ---------------------------------------------------------------------------
__global__ __launch_bounds__(256) void qkv_partial_k(
    const float* __restrict__ x, const float* __restrict__ wq,
    const float* __restrict__ wk, const float* __restrict__ wv,
    float* __restrict__ part) {
  const int cb  = blockIdx.x % 28;
  const int kc  = blockIdx.x / 28;
  const int tid = threadIdx.x;
  const int c   = cb * 256 + tid;

  const float* w; int OD, j;
  if (c < 5120)      { w = wq; OD = 5120; j = c; }
  else if (c < 6144) { w = wk; OD = 1024; j = c - 5120; }
  else               { w = wv; OD = 1024; j = c - 6144; }

  __shared__ float xs[BS * KCH];
  const int i0 = kc * KCH;
  for (int idx = tid; idx < BS * KCH; idx += 256) {
    int b = idx / KCH, ii = idx - b * KCH;
    xs[idx] = x[b * DIM + i0 + ii];
  }
  __syncthreads();

  float acc[BS];
#pragma unroll
  for (int b = 0; b < BS; ++b) acc[b] = 0.f;

  const float* wp = w + (size_t)i0 * OD + j;
  for (int ii = 0; ii < KCH; ++ii) {
    float wval = wp[(size_t)ii * OD];
#pragma unroll
    for (int b = 0; b < BS; ++b) acc[b] = fmaf(xs[b * KCH + ii], wval, acc[b]);
  }
#pragma unroll
  for (int b = 0; b < BS; ++b)
    part[((size_t)kc * BS + b) * ODQKV + c] = acc[b];
}

// ---------------------------------------------------------------------------
// Phase A2: reduce partials, add bias, apply RoPE (pos 4095), fold 1/sqrt(128)
// into q.
// ---------------------------------------------------------------------------
__global__ __launch_bounds__(256) void qkv_reduce_k(
    const float* __restrict__ part, const float* __restrict__ bq,
    const float* __restrict__ bk, const float* __restrict__ bv,
    const float* __restrict__ fc, float* __restrict__ qws,
    float* __restrict__ kws, float* __restrict__ vws) {
  int g = blockIdx.x * 256 + threadIdx.x;
  if (g >= BS * (ODQKV / 2)) return;
  int b  = g / (ODQKV / 2);
  int cp = g - b * (ODQKV / 2);
  int c0 = cp * 2;

  float sx = 0.f, sy = 0.f;
  for (int kc = 0; kc < NKC; ++kc) {
    const float2 p = *(const float2*)&part[((size_t)kc * BS + b) * ODQKV + c0];
    sx += p.x; sy += p.y;
  }

  const float scale = 0.088388347648318447f;  // 1/sqrt(128)
  if (c0 < 5120) {
    sx += bq[c0]; sy += bq[c0 + 1];
    int jf = (c0 & 127) >> 1;
    float cs = fc[2 * jf], sn = fc[2 * jf + 1];
    qws[b * DIM + c0]     = (sx * cs - sy * sn) * scale;
    qws[b * DIM + c0 + 1] = (sx * sn + sy * cs) * scale;
  } else if (c0 < 6144) {
    int jj = c0 - 5120;
    sx += bk[jj]; sy += bk[jj + 1];
    int jf = (jj & 127) >> 1;
    float cs = fc[2 * jf], sn = fc[2 * jf + 1];
    kws[b * NKV * HD + jj]     = sx * cs - sy * sn;
    kws[b * NKV * HD + jj + 1] = sx * sn + sy * cs;
  } else {
    int jj = c0 - 6144;
    vws[b * NKV * HD + jj]     = sx + bv[jj];
    vws[b * NKV * HD + jj + 1] = sy + bv[jj + 1];
  }
}

// ---------------------------------------------------------------------------
// Phase B: flash-decode partials, 16-lane-group structure.
// grid = 64 (b,h) * NCHUNK; 4 waves/block; wave = 4 groups of 16 lanes;
// group g handles t = tbase + g (4 consecutive t rows per wave step, fully
// coalesced float4 loads). 8-el dot per lane + 4-stage intra-group butterfly.
// Group accumulators merged at wave end via xor-16/32 shuffles.
// t == 4095 reads the freshly projected k/v (cache input is NOT mutated).
// ---------------------------------------------------------------------------
__global__ __launch_bounds__(256) void attn_partial_k(
    const float* __restrict__ ck, const float* __restrict__ cv,
    const float* __restrict__ qws, const float* __restrict__ kws,
    const float* __restrict__ vws, float* __restrict__ pM,
    float* __restrict__ pL, float* __restrict__ pO) {
  const int blk   = blockIdx.x;
  const int chunk = blk & (NCHUNK - 1);
  const int bh    = blk / NCHUNK;
  const int h     = bh & (NKV - 1);
  const int b     = bh / NKV;
  const int wave  = threadIdx.x >> 6;
  const int lane  = threadIdx.x & 63;
  const int grp   = lane >> 4;     // 0..3: which t within a 4-row step
  const int sl    = lane & 15;     // owns d-range [8*sl, 8*sl+8)
  const int widx  = chunk * 4 + wave;
  const int t0    = chunk * CH_T + wave * WAVE_T;

  float4 qa[NREP], qb[NREP];
#pragma unroll
  for (int r = 0; r < NREP; ++r) {
    const float* qp = &qws[b * DIM + (h * NREP + r) * HD + 8 * sl];
    qa[r] = *(const float4*)qp;
    qb[r] = *(const float4*)(qp + 4);
  }

  float m[NREP], l[NREP], o[NREP][8];
#pragma unroll
  for (int r = 0; r < NREP; ++r) {
    m[r] = -1e30f; l[r] = 0.f;
#pragma unroll
    for (int j = 0; j < 8; ++j) o[r][j] = 0.f;
  }

  const float* kbase = &ck[((size_t)b * KLEN * NKV + h) * HD];
  const float* vbase = &cv[((size_t)b * KLEN * NKV + h) * HD];
  const float* knew  = &kws[(b * NKV + h) * HD];
  const float* vnew  = &vws[(b * NKV + h) * HD];

  for (int i = 0; i < WAVE_T / 4; ++i) {
    const int t = t0 + 4 * i + grp;
    const float* kr = (t == NEWT) ? knew : kbase + (size_t)t * (NKV * HD);
    const float4 ka = *(const float4*)(kr + 8 * sl);
    const float4 kb = *(const float4*)(kr + 8 * sl + 4);

    float s[NREP];
#pragma unroll
    for (int r = 0; r < NREP; ++r) {
      s[r] = qa[r].x * ka.x + qa[r].y * ka.y + qa[r].z * ka.z + qa[r].w * ka.w
           + qb[r].x * kb.x + qb[r].y * kb.y + qb[r].z * kb.z + qb[r].w * kb.w;
    }
#pragma unroll
    for (int off = 1; off < 16; off <<= 1) {
#pragma unroll
      for (int r = 0; r < NREP; ++r) s[r] += __shfl_xor(s[r], off, 64);
    }

    const float* vr = (t == NEWT) ? vnew : vbase + (size_t)t * (NKV * HD);
    const float4 va = *(const float4*)(vr + 8 * sl);
    const float4 vb = *(const float4*)(vr + 8 * sl + 4);
    const float vv[8] = {va.x, va.y, va.z, va.w, vb.x, vb.y, vb.z, vb.w};

#pragma unroll
    for (int r = 0; r < NREP; ++r) {
      if (s[r] <= m[r]) {            // uniform within 16-lane group; rare else
        float p = __expf(s[r] - m[r]);
        l[r] += p;
#pragma unroll
        for (int j = 0; j < 8; ++j) o[r][j] = fmaf(p, vv[j], o[r][j]);
      } else {
        float rs = __expf(m[r] - s[r]);
        l[r] = fmaf(l[r], rs, 1.f);
#pragma unroll
        for (int j = 0; j < 8; ++j) o[r][j] = fmaf(o[r][j], rs, vv[j]);
        m[r] = s[r];
      }
    }
  }

  // merge the 4 groups (lanes with equal sl hold the same d-range)
#pragma unroll
  for (int off = 16; off <= 32; off <<= 1) {
#pragma unroll
    for (int r = 0; r < NREP; ++r) {
      float mo = __shfl_xor(m[r], off, 64);
      float lo = __shfl_xor(l[r], off, 64);
      float oo[8];
#pragma unroll
      for (int j = 0; j < 8; ++j) oo[j] = __shfl_xor(o[r][j], off, 64);
      float mn = fmaxf(m[r], mo);
      float ea = __expf(m[r] - mn);
      float eb = __expf(mo - mn);
      l[r] = l[r] * ea + lo * eb;
#pragma unroll
      for (int j = 0; j < 8; ++j) o[r][j] = o[r][j] * ea + oo[j] * eb;
      m[r] = mn;
    }
  }

  const int pb = bh * NPART + widx;
  if (grp == 0) {
#pragma unroll
    for (int r = 0; r < NREP; ++r) {
      float* op = &pO[((size_t)pb * NREP + r) * HD + 8 * sl];
      *(float4*)op       = make_float4(o[r][0], o[r][1], o[r][2], o[r][3]);
      *(float4*)(op + 4) = make_float4(o[r][4], o[r][5], o[r][6], o[r][7]);
    }
    if (sl == 0) {
#pragma unroll
      for (int r = 0; r < NREP; ++r) {
        pM[pb * NREP + r] = m[r];
        pL[pb * NREP + r] = l[r];
      }
    }
  }
}

// ---------------------------------------------------------------------------
// Phase B2: combine NPART partials per (b,h) with exp rescale.
// ---------------------------------------------------------------------------
__global__ __launch_bounds__(256) void attn_combine_k(
    const float* __restrict__ pM, const float* __restrict__ pL,
    const float* __restrict__ pO, float* __restrict__ attn) {
  const int bh  = blockIdx.x;
  const int h   = bh & (NKV - 1);
  const int b   = bh / NKV;
  const int tid = threadIdx.x;
  __shared__ float ml[NREP * NPART], ll[NREP * NPART];
  __shared__ float wgt[NREP * NPART];
  __shared__ float Linv[NREP];

  for (int idx = tid; idx < NREP * NPART; idx += 256) {
    int r = idx / NPART, w = idx - r * NPART;
    ml[idx] = pM[(bh * NPART + w) * NREP + r];
    ll[idx] = pL[(bh * NPART + w) * NREP + r];
  }
  __syncthreads();
  for (int idx = tid; idx < NREP * NPART; idx += 256) {
    int r = idx / NPART;
    float M = -1e30f;
    for (int w = 0; w < NPART; ++w) M = fmaxf(M, ml[r * NPART + w]);
    float e = __expf(ml[idx] - M);
    wgt[idx] = e;
    ll[idx] *= e;
  }
  __syncthreads();
  if (tid < NREP) {
    float L = 0.f;
    for (int w = 0; w < NPART; ++w) L += ll[tid * NPART + w];
    Linv[tid] = 1.f / L;
  }
  __syncthreads();

  for (int oidx = tid; oidx < NREP * HD; oidx += 256) {
    int r = oidx >> 7, d = oidx & 127;
    float acc = 0.f;
    for (int w = 0; w < NPART; ++w)
      acc += wgt[r * NPART + w] * pO[((size_t)(bh * NPART + w) * NREP + r) * HD + d];
    attn[b * DIM + (h * NREP + r) * HD + d] = acc * Linv[r];
  }
}

// ---------------------------------------------------------------------------
// Phase C: output projection GEMV (split-K) + reduce with bias.
// ---------------------------------------------------------------------------
__global__ __launch_bounds__(256) void out_partial_k(
    const float* __restrict__ attn, const float* __restrict__ wo,
    float* __restrict__ part) {
  const int cb  = blockIdx.x % 20;
  const int kc  = blockIdx.x / 20;
  const int tid = threadIdx.x;
  const int c   = cb * 256 + tid;

  __shared__ float xs[BS * KCH];
  const int i0 = kc * KCH;
  for (int idx = tid; idx < BS * KCH; idx += 256) {
    int b = idx / KCH, ii = idx - b * KCH;
    xs[idx] = attn[b * DIM + i0 + ii];
  }
  __syncthreads();

  float acc[BS];
#pragma unroll
  for (int b = 0; b < BS; ++b) acc[b] = 0.f;

  const float* wp = wo + (size_t)i0 * DIM + c;
  for (int ii = 0; ii < KCH; ++ii) {
    float wval = wp[(size_t)ii * DIM];
#pragma unroll
    for (int b = 0; b < BS; ++b) acc[b] = fmaf(xs[b * KCH + ii], wval, acc[b]);
  }
#pragma unroll
  for (int b = 0; b < BS; ++b)
    part[((size_t)kc * BS + b) * DIM + c] = acc[b];
}

__global__ __launch_bounds__(256) void out_reduce_k(
    const float* __restrict__ part, const float* __restrict__ bo,
    float* __restrict__ out) {
  int g = blockIdx.x * 256 + threadIdx.x;
  if (g >= BS * DIM) return;
  int b = g / DIM, c = g - b * DIM;
  float s = 0.f;
  for (int kc = 0; kc < NKC; ++kc) s += part[((size_t)kc * BS + b) * DIM + c];
  out[g] = s + bo[c];
}

// ---------------------------------------------------------------------------
extern "C" void kernel_launch(void* const* d_in, const int* in_sizes, int n_in,
                              void* d_out, int out_size, void* d_ws, size_t ws_size,
                              hipStream_t stream) {
  const float* x  = (const float*)d_in[0];
  // d_in[1] = start_pos (hardcoded 4095 per problem constants)
  const float* fc = (const float*)d_in[2];
  const float* ck = (const float*)d_in[3];
  const float* cv = (const float*)d_in[4];
  const float* wq = (const float*)d_in[5];
  const float* bq = (const float*)d_in[6];
  const float* wk = (const float*)d_in[7];
  const float* bk = (const float*)d_in[8];
  const float* wv = (const float*)d_in[9];
  const float* bv = (const float*)d_in[10];
  const float* wo = (const float*)d_in[11];
  const float* bo = (const float*)d_in[12];

  float* ws      = (float*)d_ws;
  float* qws     = ws + WS_Q;
  float* kws     = ws + WS_K;
  float* vws     = ws + WS_V;
  float* attn    = ws + WS_ATTN;
  float* scratch = ws + WS_SCRATCH;

  // Phase A: QKV projection
  qkv_partial_k<<<28 * NKC, 256, 0, stream>>>(x, wq, wk, wv, scratch);
  qkv_reduce_k<<<(BS * (ODQKV / 2) + 255) / 256, 256, 0, stream>>>(
      scratch, bq, bk, bv, fc, qws, kws, vws);

  // Phase B: attention (scratch reused for softmax partials)
  float* pM = scratch;
  float* pL = pM + 64 * NPART * NREP;
  float* pO = pL + 64 * NPART * NREP;
  attn_partial_k<<<64 * NCHUNK, 256, 0, stream>>>(ck, cv, qws, kws, vws, pM, pL, pO);
  attn_combine_k<<<64, 256, 0, stream>>>(pM, pL, pO, attn);

  // Phase C: output projection (scratch reused for GEMV partials)
  out_partial_k<<<20 * NKC, 256, 0, stream>>>(attn, wo, scratch);
  out_reduce_k<<<(BS * DIM + 255) / 256, 256, 0, stream>>>(scratch, bo, (float*)d_out);
}

// Round 5
// 154.974 us; speedup vs baseline: 1.7256x; 1.2480x over previous
//
#include <hip/hip_runtime.h>
#include <hip/hip_bf16.h>
#include <math.h>

#define DIM   5120
#define NH    40
#define NKV   8
#define HD    128
#define BS    8
#define KLEN  4096
#define NEWT  4095
#define NREP  5

#define ODQKV 7168          // 5120 + 1024 + 1024 combined output columns
#define NKC   32            // split-K chunks for GEMVs
#define KCH   (DIM / NKC)   // 160 rows per chunk

#define NCHUNK 16               // t-chunks per (b,h)
#define CH_T   (KLEN / NCHUNK)  // 256
#define WAVE_T (CH_T / 4)       // 64 t per wave
#define NPART  (NCHUNK * 4)     // 64 partials per (b,h)

// workspace layout (in floats)
#define WS_Q       0
#define WS_K       (WS_Q + BS * DIM)        // 40960
#define WS_V       (WS_K + BS * NKV * HD)   // 49152
#define WS_ATTN    (WS_V + BS * NKV * HD)   // 57344
#define WS_SCRATCH (WS_ATTN + BS * DIM)     // 98304  (scratch reused across phases)

// ---------------------------------------------------------------------------
// Phase A: combined QKV GEMV, split-K partials.
// 2 columns/thread (float2 weight loads), x read via wave-uniform scalar
// loads (no LDS staging). grid = 14 col-blocks (512 cols) * NKC k-chunks.
// ---------------------------------------------------------------------------
__global__ __launch_bounds__(256) void qkv_partial_k(
    const float* __restrict__ x, const float* __restrict__ wq,
    const float* __restrict__ wk, const float* __restrict__ wv,
    float* __restrict__ part) {
  const int cb = blockIdx.x % 14;
  const int kc = blockIdx.x / 14;
  const int c0 = cb * 512 + threadIdx.x * 2;   // first of 2 owned columns

  const float* w; int OD, j;
  if (c0 < 5120)      { w = wq; OD = 5120; j = c0; }
  else if (c0 < 6144) { w = wk; OD = 1024; j = c0 - 5120; }
  else                { w = wv; OD = 1024; j = c0 - 6144; }

  const int i0 = kc * KCH;
  float ax[BS], ay[BS];
#pragma unroll
  for (int b = 0; b < BS; ++b) { ax[b] = 0.f; ay[b] = 0.f; }

  const float* wp = w + (size_t)i0 * OD + j;
  const float* xp = x + i0;
#pragma unroll 4
  for (int ii = 0; ii < KCH; ++ii) {
    const float2 wv2 = *(const float2*)&wp[(size_t)ii * OD];
#pragma unroll
    for (int b = 0; b < BS; ++b) {
      const float xb = xp[b * DIM + ii];   // wave-uniform -> scalar load
      ax[b] = fmaf(xb, wv2.x, ax[b]);
      ay[b] = fmaf(xb, wv2.y, ay[b]);
    }
  }
#pragma unroll
  for (int b = 0; b < BS; ++b)
    *(float2*)&part[((size_t)kc * BS + b) * ODQKV + c0] = make_float2(ax[b], ay[b]);
}

// ---------------------------------------------------------------------------
// Phase A2: reduce partials, add bias, apply RoPE (pos 4095), fold 1/sqrt(128)
// into q.
// ---------------------------------------------------------------------------
__global__ __launch_bounds__(256) void qkv_reduce_k(
    const float* __restrict__ part, const float* __restrict__ bq,
    const float* __restrict__ bk, const float* __restrict__ bv,
    const float* __restrict__ fc, float* __restrict__ qws,
    float* __restrict__ kws, float* __restrict__ vws) {
  int g = blockIdx.x * 256 + threadIdx.x;
  if (g >= BS * (ODQKV / 2)) return;
  int b  = g / (ODQKV / 2);
  int cp = g - b * (ODQKV / 2);
  int c0 = cp * 2;

  float sx = 0.f, sy = 0.f;
  for (int kc = 0; kc < NKC; ++kc) {
    const float2 p = *(const float2*)&part[((size_t)kc * BS + b) * ODQKV + c0];
    sx += p.x; sy += p.y;
  }

  const float scale = 0.088388347648318447f;  // 1/sqrt(128)
  if (c0 < 5120) {
    sx += bq[c0]; sy += bq[c0 + 1];
    int jf = (c0 & 127) >> 1;
    float cs = fc[2 * jf], sn = fc[2 * jf + 1];
    qws[b * DIM + c0]     = (sx * cs - sy * sn) * scale;
    qws[b * DIM + c0 + 1] = (sx * sn + sy * cs) * scale;
  } else if (c0 < 6144) {
    int jj = c0 - 5120;
    sx += bk[jj]; sy += bk[jj + 1];
    int jf = (jj & 127) >> 1;
    float cs = fc[2 * jf], sn = fc[2 * jf + 1];
    kws[b * NKV * HD + jj]     = sx * cs - sy * sn;
    kws[b * NKV * HD + jj + 1] = sx * sn + sy * cs;
  } else {
    int jj = c0 - 6144;
    vws[b * NKV * HD + jj]     = sx + bv[jj];
    vws[b * NKV * HD + jj + 1] = sy + bv[jj + 1];
  }
}

// ---------------------------------------------------------------------------
// Phase B: flash-decode partials, 16-lane-group structure.
// t == 4095 reads the freshly projected k/v (cache input is NOT mutated).
// ---------------------------------------------------------------------------
__global__ __launch_bounds__(256) void attn_partial_k(
    const float* __restrict__ ck, const float* __restrict__ cv,
    const float* __restrict__ qws, const float* __restrict__ kws,
    const float* __restrict__ vws, float* __restrict__ pM,
    float* __restrict__ pL, float* __restrict__ pO) {
  const int blk   = blockIdx.x;
  const int chunk = blk & (NCHUNK - 1);
  const int bh    = blk / NCHUNK;
  const int h     = bh & (NKV - 1);
  const int b     = bh / NKV;
  const int wave  = threadIdx.x >> 6;
  const int lane  = threadIdx.x & 63;
  const int grp   = lane >> 4;     // 0..3: which t within a 4-row step
  const int sl    = lane & 15;     // owns d-range [8*sl, 8*sl+8)
  const int widx  = chunk * 4 + wave;
  const int t0    = chunk * CH_T + wave * WAVE_T;

  float4 qa[NREP], qb[NREP];
#pragma unroll
  for (int r = 0; r < NREP; ++r) {
    const float* qp = &qws[b * DIM + (h * NREP + r) * HD + 8 * sl];
    qa[r] = *(const float4*)qp;
    qb[r] = *(const float4*)(qp + 4);
  }

  float m[NREP], l[NREP], o[NREP][8];
#pragma unroll
  for (int r = 0; r < NREP; ++r) {
    m[r] = -1e30f; l[r] = 0.f;
#pragma unroll
    for (int j = 0; j < 8; ++j) o[r][j] = 0.f;
  }

  const float* kbase = &ck[((size_t)b * KLEN * NKV + h) * HD];
  const float* vbase = &cv[((size_t)b * KLEN * NKV + h) * HD];
  const float* knew  = &kws[(b * NKV + h) * HD];
  const float* vnew  = &vws[(b * NKV + h) * HD];

  for (int i = 0; i < WAVE_T / 4; ++i) {
    const int t = t0 + 4 * i + grp;
    const float* kr = (t == NEWT) ? knew : kbase + (size_t)t * (NKV * HD);
    const float4 ka = *(const float4*)(kr + 8 * sl);
    const float4 kb = *(const float4*)(kr + 8 * sl + 4);

    float s[NREP];
#pragma unroll
    for (int r = 0; r < NREP; ++r) {
      s[r] = qa[r].x * ka.x + qa[r].y * ka.y + qa[r].z * ka.z + qa[r].w * ka.w
           + qb[r].x * kb.x + qb[r].y * kb.y + qb[r].z * kb.z + qb[r].w * kb.w;
    }
#pragma unroll
    for (int off = 1; off < 16; off <<= 1) {
#pragma unroll
      for (int r = 0; r < NREP; ++r) s[r] += __shfl_xor(s[r], off, 64);
    }

    const float* vr = (t == NEWT) ? vnew : vbase + (size_t)t * (NKV * HD);
    const float4 va = *(const float4*)(vr + 8 * sl);
    const float4 vb = *(const float4*)(vr + 8 * sl + 4);
    const float vv[8] = {va.x, va.y, va.z, va.w, vb.x, vb.y, vb.z, vb.w};

#pragma unroll
    for (int r = 0; r < NREP; ++r) {
      if (s[r] <= m[r]) {            // uniform within 16-lane group; rare else
        float p = __expf(s[r] - m[r]);
        l[r] += p;
#pragma unroll
        for (int j = 0; j < 8; ++j) o[r][j] = fmaf(p, vv[j], o[r][j]);
      } else {
        float rs = __expf(m[r] - s[r]);
        l[r] = fmaf(l[r], rs, 1.f);
#pragma unroll
        for (int j = 0; j < 8; ++j) o[r][j] = fmaf(o[r][j], rs, vv[j]);
        m[r] = s[r];
      }
    }
  }

  // merge the 4 groups (lanes with equal sl hold the same d-range)
#pragma unroll
  for (int off = 16; off <= 32; off <<= 1) {
#pragma unroll
    for (int r = 0; r < NREP; ++r) {
      float mo = __shfl_xor(m[r], off, 64);
      float lo = __shfl_xor(l[r], off, 64);
      float oo[8];
#pragma unroll
      for (int j = 0; j < 8; ++j) oo[j] = __shfl_xor(o[r][j], off, 64);
      float mn = fmaxf(m[r], mo);
      float ea = __expf(m[r] - mn);
      float eb = __expf(mo - mn);
      l[r] = l[r] * ea + lo * eb;
#pragma unroll
      for (int j = 0; j < 8; ++j) o[r][j] = o[r][j] * ea + oo[j] * eb;
      m[r] = mn;
    }
  }

  const int pb = bh * NPART + widx;
  if (grp == 0) {
#pragma unroll
    for (int r = 0; r < NREP; ++r) {
      float* op = &pO[((size_t)pb * NREP + r) * HD + 8 * sl];
      *(float4*)op       = make_float4(o[r][0], o[r][1], o[r][2], o[r][3]);
      *(float4*)(op + 4) = make_float4(o[r][4], o[r][5], o[r][6], o[r][7]);
    }
    if (sl == 0) {
#pragma unroll
      for (int r = 0; r < NREP; ++r) {
        pM[pb * NREP + r] = m[r];
        pL[pb * NREP + r] = l[r];
      }
    }
  }
}

// ---------------------------------------------------------------------------
// Phase B2: combine NPART partials per (b,h) with exp rescale.
// ---------------------------------------------------------------------------
__global__ __launch_bounds__(256) void attn_combine_k(
    const float* __restrict__ pM, const float* __restrict__ pL,
    const float* __restrict__ pO, float* __restrict__ attn) {
  const int bh  = blockIdx.x;
  const int h   = bh & (NKV - 1);
  const int b   = bh / NKV;
  const int tid = threadIdx.x;
  __shared__ float ml[NREP * NPART], ll[NREP * NPART];
  __shared__ float wgt[NREP * NPART];
  __shared__ float Linv[NREP];

  for (int idx = tid; idx < NREP * NPART; idx += 256) {
    int r = idx / NPART, w = idx - r * NPART;
    ml[idx] = pM[(bh * NPART + w) * NREP + r];
    ll[idx] = pL[(bh * NPART + w) * NREP + r];
  }
  __syncthreads();
  for (int idx = tid; idx < NREP * NPART; idx += 256) {
    int r = idx / NPART;
    float M = -1e30f;
    for (int w = 0; w < NPART; ++w) M = fmaxf(M, ml[r * NPART + w]);
    float e = __expf(ml[idx] - M);
    wgt[idx] = e;
    ll[idx] *= e;
  }
  __syncthreads();
  if (tid < NREP) {
    float L = 0.f;
    for (int w = 0; w < NPART; ++w) L += ll[tid * NPART + w];
    Linv[tid] = 1.f / L;
  }
  __syncthreads();

  for (int oidx = tid; oidx < NREP * HD; oidx += 256) {
    int r = oidx >> 7, d = oidx & 127;
    float acc = 0.f;
    for (int w = 0; w < NPART; ++w)
      acc += wgt[r * NPART + w] * pO[((size_t)(bh * NPART + w) * NREP + r) * HD + d];
    attn[b * DIM + (h * NREP + r) * HD + d] = acc * Linv[r];
  }
}

// ---------------------------------------------------------------------------
// Phase C: output projection GEMV (split-K, 2 cols/thread) + reduce with bias.
// ---------------------------------------------------------------------------
__global__ __launch_bounds__(256) void out_partial_k(
    const float* __restrict__ attn, const float* __restrict__ wo,
    float* __restrict__ part) {
  const int cb = blockIdx.x % 10;
  const int kc = blockIdx.x / 10;
  const int c0 = cb * 512 + threadIdx.x * 2;

  const int i0 = kc * KCH;
  float ax[BS], ay[BS];
#pragma unroll
  for (int b = 0; b < BS; ++b) { ax[b] = 0.f; ay[b] = 0.f; }

  const float* wp = wo + (size_t)i0 * DIM + c0;
  const float* xp = attn + i0;
#pragma unroll 4
  for (int ii = 0; ii < KCH; ++ii) {
    const float2 wv2 = *(const float2*)&wp[(size_t)ii * DIM];
#pragma unroll
    for (int b = 0; b < BS; ++b) {
      const float xb = xp[b * DIM + ii];   // wave-uniform -> scalar load
      ax[b] = fmaf(xb, wv2.x, ax[b]);
      ay[b] = fmaf(xb, wv2.y, ay[b]);
    }
  }
#pragma unroll
  for (int b = 0; b < BS; ++b)
    *(float2*)&part[((size_t)kc * BS + b) * DIM + c0] = make_float2(ax[b], ay[b]);
}

__global__ __launch_bounds__(256) void out_reduce_k(
    const float* __restrict__ part, const float* __restrict__ bo,
    float* __restrict__ out) {
  int g = blockIdx.x * 256 + threadIdx.x;
  if (g >= BS * DIM) return;
  int b = g / DIM, c = g - b * DIM;
  float s = 0.f;
  for (int kc = 0; kc < NKC; ++kc) s += part[((size_t)kc * BS + b) * DIM + c];
  out[g] = s + bo[c];
}

// ---------------------------------------------------------------------------
extern "C" void kernel_launch(void* const* d_in, const int* in_sizes, int n_in,
                              void* d_out, int out_size, void* d_ws, size_t ws_size,
                              hipStream_t stream) {
  const float* x  = (const float*)d_in[0];
  // d_in[1] = start_pos (hardcoded 4095 per problem constants)
  const float* fc = (const float*)d_in[2];
  const float* ck = (const float*)d_in[3];
  const float* cv = (const float*)d_in[4];
  const float* wq = (const float*)d_in[5];
  const float* bq = (const float*)d_in[6];
  const float* wk = (const float*)d_in[7];
  const float* bk = (const float*)d_in[8];
  const float* wv = (const float*)d_in[9];
  const float* bv = (const float*)d_in[10];
  const float* wo = (const float*)d_in[11];
  const float* bo = (const float*)d_in[12];

  float* ws      = (float*)d_ws;
  float* qws     = ws + WS_Q;
  float* kws     = ws + WS_K;
  float* vws     = ws + WS_V;
  float* attn    = ws + WS_ATTN;
  float* scratch = ws + WS_SCRATCH;

  // Phase A: QKV projection
  qkv_partial_k<<<14 * NKC, 256, 0, stream>>>(x, wq, wk, wv, scratch);
  qkv_reduce_k<<<(BS * (ODQKV / 2) + 255) / 256, 256, 0, stream>>>(
      scratch, bq, bk, bv, fc, qws, kws, vws);

  // Phase B: attention (scratch reused for softmax partials)
  float* pM = scratch;
  float* pL = pM + 64 * NPART * NREP;
  float* pO = pL + 64 * NPART * NREP;
  attn_partial_k<<<64 * NCHUNK, 256, 0, stream>>>(ck, cv, qws, kws, vws, pM, pL, pO);
  attn_combine_k<<<64, 256, 0, stream>>>(pM, pL, pO, attn);

  // Phase C: output projection (scratch reused for GEMV partials)
  out_partial_k<<<10 * NKC, 256, 0, stream>>>(attn, wo, scratch);
  out_reduce_k<<<(BS * DIM + 255) / 256, 256, 0, stream>>>(scratch, bo, (float*)d_out);
}

// Round 6
// 139.533 us; speedup vs baseline: 1.9166x; 1.1107x over previous
//
#include <hip/hip_runtime.h>
#include <hip/hip_bf16.h>
#include <math.h>

#define DIM   5120
#define NH    40
#define NKV   8
#define HD    128
#define BS    8
#define KLEN  4096
#define NEWT  4095
#define NREP  5

#define ODQKV 7168          // 5120 + 1024 + 1024 combined output columns
#define NKC   32            // split-K chunks for GEMVs
#define KCH   (DIM / NKC)   // 160 rows per chunk

#define NCHUNK 32               // t-chunks per (b,h) = blocks per (b,h)
#define CH_T   (KLEN / NCHUNK)  // 128 t per block
#define WAVE_T (CH_T / 4)       // 32 t per wave
#define NPART  NCHUNK           // one partial per block (waves merged in LDS)

// workspace layout (in floats)
#define WS_Q       0
#define WS_K       (WS_Q + BS * DIM)        // 40960
#define WS_V       (WS_K + BS * NKV * HD)   // 49152
#define WS_ATTN    (WS_V + BS * NKV * HD)   // 57344
#define WS_SCRATCH (WS_ATTN + BS * DIM)     // 98304  (scratch reused across phases)

// ---------------------------------------------------------------------------
// Phase A: combined QKV GEMV, split-K partials. 2 cols/thread, float2 weight
// loads, x via wave-uniform scalar loads.
// ---------------------------------------------------------------------------
__global__ __launch_bounds__(256) void qkv_partial_k(
    const float* __restrict__ x, const float* __restrict__ wq,
    const float* __restrict__ wk, const float* __restrict__ wv,
    float* __restrict__ part) {
  const int cb = blockIdx.x % 14;
  const int kc = blockIdx.x / 14;
  const int c0 = cb * 512 + threadIdx.x * 2;   // first of 2 owned columns

  const float* w; int OD, j;
  if (c0 < 5120)      { w = wq; OD = 5120; j = c0; }
  else if (c0 < 6144) { w = wk; OD = 1024; j = c0 - 5120; }
  else                { w = wv; OD = 1024; j = c0 - 6144; }

  const int i0 = kc * KCH;
  float ax[BS], ay[BS];
#pragma unroll
  for (int b = 0; b < BS; ++b) { ax[b] = 0.f; ay[b] = 0.f; }

  const float* wp = w + (size_t)i0 * OD + j;
  const float* xp = x + i0;
#pragma unroll 4
  for (int ii = 0; ii < KCH; ++ii) {
    const float2 wv2 = *(const float2*)&wp[(size_t)ii * OD];
#pragma unroll
    for (int b = 0; b < BS; ++b) {
      const float xb = xp[b * DIM + ii];   // wave-uniform -> scalar load
      ax[b] = fmaf(xb, wv2.x, ax[b]);
      ay[b] = fmaf(xb, wv2.y, ay[b]);
    }
  }
#pragma unroll
  for (int b = 0; b < BS; ++b)
    *(float2*)&part[((size_t)kc * BS + b) * ODQKV + c0] = make_float2(ax[b], ay[b]);
}

// ---------------------------------------------------------------------------
// Phase A2: reduce partials, add bias, apply RoPE (pos 4095), fold 1/sqrt(128)
// into q.
// ---------------------------------------------------------------------------
__global__ __launch_bounds__(256) void qkv_reduce_k(
    const float* __restrict__ part, const float* __restrict__ bq,
    const float* __restrict__ bk, const float* __restrict__ bv,
    const float* __restrict__ fc, float* __restrict__ qws,
    float* __restrict__ kws, float* __restrict__ vws) {
  int g = blockIdx.x * 256 + threadIdx.x;
  if (g >= BS * (ODQKV / 2)) return;
  int b  = g / (ODQKV / 2);
  int cp = g - b * (ODQKV / 2);
  int c0 = cp * 2;

  float sx = 0.f, sy = 0.f;
  for (int kc = 0; kc < NKC; ++kc) {
    const float2 p = *(const float2*)&part[((size_t)kc * BS + b) * ODQKV + c0];
    sx += p.x; sy += p.y;
  }

  const float scale = 0.088388347648318447f;  // 1/sqrt(128)
  if (c0 < 5120) {
    sx += bq[c0]; sy += bq[c0 + 1];
    int jf = (c0 & 127) >> 1;
    float cs = fc[2 * jf], sn = fc[2 * jf + 1];
    qws[b * DIM + c0]     = (sx * cs - sy * sn) * scale;
    qws[b * DIM + c0 + 1] = (sx * sn + sy * cs) * scale;
  } else if (c0 < 6144) {
    int jj = c0 - 5120;
    sx += bk[jj]; sy += bk[jj + 1];
    int jf = (jj & 127) >> 1;
    float cs = fc[2 * jf], sn = fc[2 * jf + 1];
    kws[b * NKV * HD + jj]     = sx * cs - sy * sn;
    kws[b * NKV * HD + jj + 1] = sx * sn + sy * cs;
  } else {
    int jj = c0 - 6144;
    vws[b * NKV * HD + jj]     = sx + bv[jj];
    vws[b * NKV * HD + jj + 1] = sy + bv[jj + 1];
  }
}

// ---------------------------------------------------------------------------
// Phase B: flash-decode partials. grid = 64 (b,h) * NCHUNK blocks; 4 waves
// each own 32 t. Wave = 4 groups of 16 lanes; group g handles t = base + g.
// Main loop has NO newt conditional (affine addressing, unroll 2); the single
// wave containing t=4095 runs one tail step reading the fresh k/v.
// Waves merge their (m,l,o) in LDS -> ONE partial per block.
// ---------------------------------------------------------------------------
__global__ __launch_bounds__(256) void attn_partial_k(
    const float* __restrict__ ck, const float* __restrict__ cv,
    const float* __restrict__ qws, const float* __restrict__ kws,
    const float* __restrict__ vws, float* __restrict__ pM,
    float* __restrict__ pL, float* __restrict__ pO) {
  const int blk   = blockIdx.x;
  const int chunk = blk & (NCHUNK - 1);
  const int bh    = blk / NCHUNK;
  const int h     = bh & (NKV - 1);
  const int b     = bh / NKV;
  const int wave  = threadIdx.x >> 6;
  const int lane  = threadIdx.x & 63;
  const int grp   = lane >> 4;     // 0..3: which t within a 4-row step
  const int sl    = lane & 15;     // owns d-range [8*sl, 8*sl+8)
  const int t0    = chunk * CH_T + wave * WAVE_T;

  float4 qa[NREP], qb[NREP];
#pragma unroll
  for (int r = 0; r < NREP; ++r) {
    const float* qp = &qws[b * DIM + (h * NREP + r) * HD + 8 * sl];
    qa[r] = *(const float4*)qp;
    qb[r] = *(const float4*)(qp + 4);
  }

  float m[NREP], l[NREP], o[NREP][8];
#pragma unroll
  for (int r = 0; r < NREP; ++r) {
    m[r] = -1e30f; l[r] = 0.f;
#pragma unroll
    for (int j = 0; j < 8; ++j) o[r][j] = 0.f;
  }

  const float* kbase = &ck[((size_t)b * KLEN * NKV + h) * HD];
  const float* vbase = &cv[((size_t)b * KLEN * NKV + h) * HD];

  auto step = [&](const float4 ka, const float4 kb,
                  const float4 va, const float4 vb) {
    float s[NREP];
#pragma unroll
    for (int r = 0; r < NREP; ++r) {
      s[r] = qa[r].x * ka.x + qa[r].y * ka.y + qa[r].z * ka.z + qa[r].w * ka.w
           + qb[r].x * kb.x + qb[r].y * kb.y + qb[r].z * kb.z + qb[r].w * kb.w;
    }
#pragma unroll
    for (int off = 1; off < 16; off <<= 1) {
#pragma unroll
      for (int r = 0; r < NREP; ++r) s[r] += __shfl_xor(s[r], off, 64);
    }
    const float vv[8] = {va.x, va.y, va.z, va.w, vb.x, vb.y, vb.z, vb.w};
#pragma unroll
    for (int r = 0; r < NREP; ++r) {
      if (s[r] <= m[r]) {            // uniform within 16-lane group
        float p = __expf(s[r] - m[r]);
        l[r] += p;
#pragma unroll
        for (int j = 0; j < 8; ++j) o[r][j] = fmaf(p, vv[j], o[r][j]);
      } else {
        float rs = __expf(m[r] - s[r]);
        l[r] = fmaf(l[r], rs, 1.f);
#pragma unroll
        for (int j = 0; j < 8; ++j) o[r][j] = fmaf(o[r][j], rs, vv[j]);
        m[r] = s[r];
      }
    }
  };

  int niter = WAVE_T / 4;                       // 8
  const bool tail = (t0 + WAVE_T - 1 == NEWT);  // only chunk 31, wave 3
  if (tail) --niter;

  const float* kp = kbase + (size_t)(t0 + grp) * (NKV * HD) + 8 * sl;
  const float* vp = vbase + (size_t)(t0 + grp) * (NKV * HD) + 8 * sl;
#pragma unroll 2
  for (int i = 0; i < niter; ++i) {
    const float4 ka = *(const float4*)kp;
    const float4 kb = *(const float4*)(kp + 4);
    const float4 va = *(const float4*)vp;
    const float4 vb = *(const float4*)(vp + 4);
    kp += 4 * NKV * HD;
    vp += 4 * NKV * HD;
    step(ka, kb, va, vb);
  }
  if (tail) {
    const int t = t0 + WAVE_T - 4 + grp;        // 4092..4095
    const float* kr = (t == NEWT) ? &kws[(b * NKV + h) * HD]
                                  : kbase + (size_t)t * (NKV * HD);
    const float* vr = (t == NEWT) ? &vws[(b * NKV + h) * HD]
                                  : vbase + (size_t)t * (NKV * HD);
    const float4 ka = *(const float4*)(kr + 8 * sl);
    const float4 kb = *(const float4*)(kr + 8 * sl + 4);
    const float4 va = *(const float4*)(vr + 8 * sl);
    const float4 vb = *(const float4*)(vr + 8 * sl + 4);
    step(ka, kb, va, vb);
  }

  // merge the 4 groups (lanes with equal sl converge via butterfly)
#pragma unroll
  for (int off = 16; off <= 32; off <<= 1) {
#pragma unroll
    for (int r = 0; r < NREP; ++r) {
      float mo = __shfl_xor(m[r], off, 64);
      float lo = __shfl_xor(l[r], off, 64);
      float oo[8];
#pragma unroll
      for (int j = 0; j < 8; ++j) oo[j] = __shfl_xor(o[r][j], off, 64);
      float mn = fmaxf(m[r], mo);
      float ea = __expf(m[r] - mn);
      float eb = __expf(mo - mn);
      l[r] = l[r] * ea + lo * eb;
#pragma unroll
      for (int j = 0; j < 8; ++j) o[r][j] = o[r][j] * ea + oo[j] * eb;
      m[r] = mn;
    }
  }

  // merge the 4 waves via LDS -> one partial per block
  __shared__ float smO[4][NREP][HD];
  __shared__ float smM[4][NREP], smL[4][NREP];
  if (grp == 0) {
#pragma unroll
    for (int r = 0; r < NREP; ++r) {
      float* sp = &smO[wave][r][8 * sl];
      *(float4*)sp       = make_float4(o[r][0], o[r][1], o[r][2], o[r][3]);
      *(float4*)(sp + 4) = make_float4(o[r][4], o[r][5], o[r][6], o[r][7]);
    }
    if (sl == 0) {
#pragma unroll
      for (int r = 0; r < NREP; ++r) { smM[wave][r] = m[r]; smL[wave][r] = l[r]; }
    }
  }
  __syncthreads();

  const int tid = threadIdx.x;
  if (tid < HD) {
    const int d  = tid;
    const int pb = bh * NCHUNK + chunk;
#pragma unroll
    for (int r = 0; r < NREP; ++r) {
      float M = fmaxf(fmaxf(smM[0][r], smM[1][r]), fmaxf(smM[2][r], smM[3][r]));
      float acc = 0.f, lsum = 0.f;
#pragma unroll
      for (int w = 0; w < 4; ++w) {
        float e = __expf(smM[w][r] - M);
        acc  = fmaf(e, smO[w][r][d], acc);
        lsum = fmaf(e, smL[w][r], lsum);
      }
      pO[((size_t)pb * NREP + r) * HD + d] = acc;
      if (d == 0) { pM[pb * NREP + r] = M; pL[pb * NREP + r] = lsum; }
    }
  }
}

// ---------------------------------------------------------------------------
// Phase B2: combine NPART partials per (b,h) with exp rescale.
// ---------------------------------------------------------------------------
__global__ __launch_bounds__(256) void attn_combine_k(
    const float* __restrict__ pM, const float* __restrict__ pL,
    const float* __restrict__ pO, float* __restrict__ attn) {
  const int bh  = blockIdx.x;
  const int h   = bh & (NKV - 1);
  const int b   = bh / NKV;
  const int tid = threadIdx.x;
  __shared__ float ml[NREP * NPART], ll[NREP * NPART];
  __shared__ float wgt[NREP * NPART];
  __shared__ float Linv[NREP];

  for (int idx = tid; idx < NREP * NPART; idx += 256) {
    int r = idx / NPART, w = idx - r * NPART;
    ml[idx] = pM[(bh * NPART + w) * NREP + r];
    ll[idx] = pL[(bh * NPART + w) * NREP + r];
  }
  __syncthreads();
  for (int idx = tid; idx < NREP * NPART; idx += 256) {
    int r = idx / NPART;
    float M = -1e30f;
    for (int w = 0; w < NPART; ++w) M = fmaxf(M, ml[r * NPART + w]);
    float e = __expf(ml[idx] - M);
    wgt[idx] = e;
    ll[idx] *= e;
  }
  __syncthreads();
  if (tid < NREP) {
    float L = 0.f;
    for (int w = 0; w < NPART; ++w) L += ll[tid * NPART + w];
    Linv[tid] = 1.f / L;
  }
  __syncthreads();

  for (int oidx = tid; oidx < NREP * HD; oidx += 256) {
    int r = oidx >> 7, d = oidx & 127;
    float acc = 0.f;
    for (int w = 0; w < NPART; ++w)
      acc += wgt[r * NPART + w] * pO[((size_t)(bh * NPART + w) * NREP + r) * HD + d];
    attn[b * DIM + (h * NREP + r) * HD + d] = acc * Linv[r];
  }
}

// ---------------------------------------------------------------------------
// Phase C: output projection GEMV (split-K, 2 cols/thread) + reduce with bias.
// ---------------------------------------------------------------------------
__global__ __launch_bounds__(256) void out_partial_k(
    const float* __restrict__ attn, const float* __restrict__ wo,
    float* __restrict__ part) {
  const int cb = blockIdx.x % 10;
  const int kc = blockIdx.x / 10;
  const int c0 = cb * 512 + threadIdx.x * 2;

  const int i0 = kc * KCH;
  float ax[BS], ay[BS];
#pragma unroll
  for (int b = 0; b < BS; ++b) { ax[b] = 0.f; ay[b] = 0.f; }

  const float* wp = wo + (size_t)i0 * DIM + c0;
  const float* xp = attn + i0;
#pragma unroll 4
  for (int ii = 0; ii < KCH; ++ii) {
    const float2 wv2 = *(const float2*)&wp[(size_t)ii * DIM];
#pragma unroll
    for (int b = 0; b < BS; ++b) {
      const float xb = xp[b * DIM + ii];   // wave-uniform -> scalar load
      ax[b] = fmaf(xb, wv2.x, ax[b]);
      ay[b] = fmaf(xb, wv2.y, ay[b]);
    }
  }
#pragma unroll
  for (int b = 0; b < BS; ++b)
    *(float2*)&part[((size_t)kc * BS + b) * DIM + c0] = make_float2(ax[b], ay[b]);
}

__global__ __launch_bounds__(256) void out_reduce_k(
    const float* __restrict__ part, const float* __restrict__ bo,
    float* __restrict__ out) {
  int g = blockIdx.x * 256 + threadIdx.x;
  if (g >= BS * DIM) return;
  int b = g / DIM, c = g - b * DIM;
  float s = 0.f;
  for (int kc = 0; kc < NKC; ++kc) s += part[((size_t)kc * BS + b) * DIM + c];
  out[g] = s + bo[c];
}

// ---------------------------------------------------------------------------
extern "C" void kernel_launch(void* const* d_in, const int* in_sizes, int n_in,
                              void* d_out, int out_size, void* d_ws, size_t ws_size,
                              hipStream_t stream) {
  const float* x  = (const float*)d_in[0];
  // d_in[1] = start_pos (hardcoded 4095 per problem constants)
  const float* fc = (const float*)d_in[2];
  const float* ck = (const float*)d_in[3];
  const float* cv = (const float*)d_in[4];
  const float* wq = (const float*)d_in[5];
  const float* bq = (const float*)d_in[6];
  const float* wk = (const float*)d_in[7];
  const float* bk = (const float*)d_in[8];
  const float* wv = (const float*)d_in[9];
  const float* bv = (const float*)d_in[10];
  const float* wo = (const float*)d_in[11];
  const float* bo = (const float*)d_in[12];

  float* ws      = (float*)d_ws;
  float* qws     = ws + WS_Q;
  float* kws     = ws + WS_K;
  float* vws     = ws + WS_V;
  float* attn    = ws + WS_ATTN;
  float* scratch = ws + WS_SCRATCH;

  // Phase A: QKV projection
  qkv_partial_k<<<14 * NKC, 256, 0, stream>>>(x, wq, wk, wv, scratch);
  qkv_reduce_k<<<(BS * (ODQKV / 2) + 255) / 256, 256, 0, stream>>>(
      scratch, bq, bk, bv, fc, qws, kws, vws);

  // Phase B: attention (scratch reused for softmax partials)
  float* pM = scratch;
  float* pL = pM + 64 * NPART * NREP;
  float* pO = pL + 64 * NPART * NREP;
  attn_partial_k<<<64 * NCHUNK, 256, 0, stream>>>(ck, cv, qws, kws, vws, pM, pL, pO);
  attn_combine_k<<<64, 256, 0, stream>>>(pM, pL, pO, attn);

  // Phase C: output projection (scratch reused for GEMV partials)
  out_partial_k<<<10 * NKC, 256, 0, stream>>>(attn, wo, scratch);
  out_reduce_k<<<(BS * DIM + 255) / 256, 256, 0, stream>>>(scratch, bo, (float*)d_out);
}

// Round 7
// 130.904 us; speedup vs baseline: 2.0429x; 1.0659x over previous
//
#include <hip/hip_runtime.h>
#include <hip/hip_bf16.h>
#include <math.h>

#define DIM   5120
#define NH    40
#define NKV   8
#define HD    128
#define BS    8
#define KLEN  4096
#define NEWT  4095
#define NREP  5

#define ODQKV 7168          // 5120 + 1024 + 1024 combined output columns
#define NKC   32            // split-K chunks for GEMVs
#define KCH   (DIM / NKC)   // 160 rows per chunk

#define NCHUNK 32               // t-chunks per (b,h) = blocks per (b,h)
#define CH_T   (KLEN / NCHUNK)  // 128 t per block
#define WAVE_T (CH_T / 4)       // 32 t per wave
#define NPART  NCHUNK           // one partial per block

// workspace layout (in floats)
#define WS_Q       0
#define WS_K       (WS_Q + BS * DIM)        // 40960
#define WS_V       (WS_K + BS * NKV * HD)   // 49152
#define WS_ATTN    (WS_V + BS * NKV * HD)   // 57344
#define WS_SCRATCH (WS_ATTN + BS * DIM)     // 98304  (scratch reused across phases)

// ---------------------------------------------------------------------------
// Phase A: combined QKV GEMV, split-K partials. 2 cols/thread, float2 weight
// loads, x via wave-uniform scalar loads.
// ---------------------------------------------------------------------------
__global__ __launch_bounds__(256) void qkv_partial_k(
    const float* __restrict__ x, const float* __restrict__ wq,
    const float* __restrict__ wk, const float* __restrict__ wv,
    float* __restrict__ part) {
  const int cb = blockIdx.x % 14;
  const int kc = blockIdx.x / 14;
  const int c0 = cb * 512 + threadIdx.x * 2;   // first of 2 owned columns

  const float* w; int OD, j;
  if (c0 < 5120)      { w = wq; OD = 5120; j = c0; }
  else if (c0 < 6144) { w = wk; OD = 1024; j = c0 - 5120; }
  else                { w = wv; OD = 1024; j = c0 - 6144; }

  const int i0 = kc * KCH;
  float ax[BS], ay[BS];
#pragma unroll
  for (int b = 0; b < BS; ++b) { ax[b] = 0.f; ay[b] = 0.f; }

  const float* wp = w + (size_t)i0 * OD + j;
  const float* xp = x + i0;
#pragma unroll 4
  for (int ii = 0; ii < KCH; ++ii) {
    const float2 wv2 = *(const float2*)&wp[(size_t)ii * OD];
#pragma unroll
    for (int b = 0; b < BS; ++b) {
      const float xb = xp[b * DIM + ii];   // wave-uniform -> scalar load
      ax[b] = fmaf(xb, wv2.x, ax[b]);
      ay[b] = fmaf(xb, wv2.y, ay[b]);
    }
  }
#pragma unroll
  for (int b = 0; b < BS; ++b)
    *(float2*)&part[((size_t)kc * BS + b) * ODQKV + c0] = make_float2(ax[b], ay[b]);
}

// ---------------------------------------------------------------------------
// Phase A2: reduce partials, add bias, apply RoPE (pos 4095), fold 1/sqrt(128)
// into q.
// ---------------------------------------------------------------------------
__global__ __launch_bounds__(256) void qkv_reduce_k(
    const float* __restrict__ part, const float* __restrict__ bq,
    const float* __restrict__ bk, const float* __restrict__ bv,
    const float* __restrict__ fc, float* __restrict__ qws,
    float* __restrict__ kws, float* __restrict__ vws) {
  int g = blockIdx.x * 256 + threadIdx.x;
  if (g >= BS * (ODQKV / 2)) return;
  int b  = g / (ODQKV / 2);
  int cp = g - b * (ODQKV / 2);
  int c0 = cp * 2;

  float sx = 0.f, sy = 0.f;
  for (int kc = 0; kc < NKC; ++kc) {
    const float2 p = *(const float2*)&part[((size_t)kc * BS + b) * ODQKV + c0];
    sx += p.x; sy += p.y;
  }

  const float scale = 0.088388347648318447f;  // 1/sqrt(128)
  if (c0 < 5120) {
    sx += bq[c0]; sy += bq[c0 + 1];
    int jf = (c0 & 127) >> 1;
    float cs = fc[2 * jf], sn = fc[2 * jf + 1];
    qws[b * DIM + c0]     = (sx * cs - sy * sn) * scale;
    qws[b * DIM + c0 + 1] = (sx * sn + sy * cs) * scale;
  } else if (c0 < 6144) {
    int jj = c0 - 5120;
    sx += bk[jj]; sy += bk[jj + 1];
    int jf = (jj & 127) >> 1;
    float cs = fc[2 * jf], sn = fc[2 * jf + 1];
    kws[b * NKV * HD + jj]     = sx * cs - sy * sn;
    kws[b * NKV * HD + jj + 1] = sx * sn + sy * cs;
  } else {
    int jj = c0 - 6144;
    vws[b * NKV * HD + jj]     = sx + bv[jj];
    vws[b * NKV * HD + jj + 1] = sy + bv[jj + 1];
  }
}

// ---------------------------------------------------------------------------
// Phase B: flash-decode partials, 3-phase block structure (no online softmax):
//   P1: K-only — dot + 16-lane butterfly, raw s -> LDS (2 loads/step, unroll4)
//   P2: block max per r, p = exp(s-M) materialized in LDS, row sums
//   P3: V-only streaming — o += p*v, p via LDS broadcast (no dependencies)
// Wave = 4 groups of 16 lanes; group owns t = base+grp. Tail wave handles
// t=4095 from the fresh k/v (cache input NOT mutated). One partial per block.
// ---------------------------------------------------------------------------
__global__ __launch_bounds__(256) void attn_partial_k(
    const float* __restrict__ ck, const float* __restrict__ cv,
    const float* __restrict__ qws, const float* __restrict__ kws,
    const float* __restrict__ vws, float* __restrict__ pM,
    float* __restrict__ pL, float* __restrict__ pO) {
  const int blk   = blockIdx.x;
  const int chunk = blk & (NCHUNK - 1);
  const int bh    = blk / NCHUNK;
  const int h     = bh & (NKV - 1);
  const int b     = bh / NKV;
  const int tid   = threadIdx.x;
  const int wave  = tid >> 6;
  const int lane  = tid & 63;
  const int grp   = lane >> 4;     // 0..3: which t within a 4-row step
  const int sl    = lane & 15;     // owns d-range [8*sl, 8*sl+8)
  const int t0    = chunk * CH_T + wave * WAVE_T;

  __shared__ float s_lds[CH_T * NREP];   // raw scores, then p-values
  __shared__ float red[NREP * 8];        // segment max/sum scratch
  __shared__ float Msh[NREP], Lsh[NREP];
  __shared__ float smO[4][NREP][HD];     // per-wave output partials

  float4 qa[NREP], qb[NREP];
#pragma unroll
  for (int r = 0; r < NREP; ++r) {
    const float* qp = &qws[b * DIM + (h * NREP + r) * HD + 8 * sl];
    qa[r] = *(const float4*)qp;
    qb[r] = *(const float4*)(qp + 4);
  }

  const float* kbase = &ck[((size_t)b * KLEN * NKV + h) * HD];
  const float* vbase = &cv[((size_t)b * KLEN * NKV + h) * HD];

  int niter = WAVE_T / 4;                       // 8
  const bool tailw = (t0 + WAVE_T == KLEN);     // chunk 31, wave 3 only
  if (tailw) --niter;

  // ---- Phase 1: scores ----
  {
    const float* kp = kbase + (size_t)(t0 + grp) * (NKV * HD) + 8 * sl;
#pragma unroll 4
    for (int i = 0; i < niter; ++i) {
      const float4 ka = *(const float4*)kp;
      const float4 kb = *(const float4*)(kp + 4);
      kp += 4 * NKV * HD;
      float s[NREP];
#pragma unroll
      for (int r = 0; r < NREP; ++r) {
        s[r] = qa[r].x * ka.x + qa[r].y * ka.y + qa[r].z * ka.z + qa[r].w * ka.w
             + qb[r].x * kb.x + qb[r].y * kb.y + qb[r].z * kb.z + qb[r].w * kb.w;
      }
#pragma unroll
      for (int off = 1; off < 16; off <<= 1) {
#pragma unroll
        for (int r = 0; r < NREP; ++r) s[r] += __shfl_xor(s[r], off, 64);
      }
      const int tl = wave * WAVE_T + 4 * i + grp;
      float sv = (sl == 0) ? s[0] : (sl == 1) ? s[1] : (sl == 2) ? s[2]
               : (sl == 3) ? s[3] : s[4];
      if (sl < NREP) s_lds[tl * NREP + sl] = sv;
    }
    if (tailw) {
      const int t  = t0 + WAVE_T - 4 + grp;     // 4092..4095
      const float* kr = (t == NEWT) ? &kws[(b * NKV + h) * HD]
                                    : kbase + (size_t)t * (NKV * HD);
      const float4 ka = *(const float4*)(kr + 8 * sl);
      const float4 kb = *(const float4*)(kr + 8 * sl + 4);
      float s[NREP];
#pragma unroll
      for (int r = 0; r < NREP; ++r) {
        s[r] = qa[r].x * ka.x + qa[r].y * ka.y + qa[r].z * ka.z + qa[r].w * ka.w
             + qb[r].x * kb.x + qb[r].y * kb.y + qb[r].z * kb.z + qb[r].w * kb.w;
      }
#pragma unroll
      for (int off = 1; off < 16; off <<= 1) {
#pragma unroll
        for (int r = 0; r < NREP; ++r) s[r] += __shfl_xor(s[r], off, 64);
      }
      const int tl = wave * WAVE_T + WAVE_T - 4 + grp;
      float sv = (sl == 0) ? s[0] : (sl == 1) ? s[1] : (sl == 2) ? s[2]
               : (sl == 3) ? s[3] : s[4];
      if (sl < NREP) s_lds[tl * NREP + sl] = sv;
    }
  }
  __syncthreads();

  // ---- Phase 2: softmax (block scope) ----
  if (tid < NREP * 8) {                      // (a) segment maxima
    const int r = tid >> 3, seg = tid & 7;
    float mx = -1e30f;
    for (int k = 0; k < 16; ++k) mx = fmaxf(mx, s_lds[(seg * 16 + k) * NREP + r]);
    red[tid] = mx;
  }
  __syncthreads();
  if (tid < NREP) {                          // (b) final max
    float mx = red[tid * 8];
    for (int k = 1; k < 8; ++k) mx = fmaxf(mx, red[tid * 8 + k]);
    Msh[tid] = mx;
  }
  __syncthreads();
  for (int idx = tid; idx < CH_T * NREP; idx += 256)   // (c) p = exp(s-M)
    s_lds[idx] = __expf(s_lds[idx] - Msh[idx % NREP]);
  __syncthreads();
  if (tid < NREP * 8) {                      // (d) segment sums
    const int r = tid >> 3, seg = tid & 7;
    float sm = 0.f;
    for (int k = 0; k < 16; ++k) sm += s_lds[(seg * 16 + k) * NREP + r];
    red[tid] = sm;
  }
  __syncthreads();
  if (tid < NREP) {                          // (e) row sum
    float L = 0.f;
    for (int k = 0; k < 8; ++k) L += red[tid * 8 + k];
    Lsh[tid] = L;
  }

  // ---- Phase 3: PV streaming ----
  float o[NREP][8];
#pragma unroll
  for (int r = 0; r < NREP; ++r)
#pragma unroll
    for (int j = 0; j < 8; ++j) o[r][j] = 0.f;

  {
    const float* vp = vbase + (size_t)(t0 + grp) * (NKV * HD) + 8 * sl;
#pragma unroll 4
    for (int i = 0; i < niter; ++i) {
      const float4 va = *(const float4*)vp;
      const float4 vb = *(const float4*)(vp + 4);
      vp += 4 * NKV * HD;
      const int tl = wave * WAVE_T + 4 * i + grp;
      float p[NREP];
#pragma unroll
      for (int r = 0; r < NREP; ++r) p[r] = s_lds[tl * NREP + r];  // broadcast
      const float vv[8] = {va.x, va.y, va.z, va.w, vb.x, vb.y, vb.z, vb.w};
#pragma unroll
      for (int r = 0; r < NREP; ++r)
#pragma unroll
        for (int j = 0; j < 8; ++j) o[r][j] = fmaf(p[r], vv[j], o[r][j]);
    }
    if (tailw) {
      const int t  = t0 + WAVE_T - 4 + grp;
      const float* vr = (t == NEWT) ? &vws[(b * NKV + h) * HD]
                                    : vbase + (size_t)t * (NKV * HD);
      const float4 va = *(const float4*)(vr + 8 * sl);
      const float4 vb = *(const float4*)(vr + 8 * sl + 4);
      const int tl = wave * WAVE_T + WAVE_T - 4 + grp;
      float p[NREP];
#pragma unroll
      for (int r = 0; r < NREP; ++r) p[r] = s_lds[tl * NREP + r];
      const float vv[8] = {va.x, va.y, va.z, va.w, vb.x, vb.y, vb.z, vb.w};
#pragma unroll
      for (int r = 0; r < NREP; ++r)
#pragma unroll
        for (int j = 0; j < 8; ++j) o[r][j] = fmaf(p[r], vv[j], o[r][j]);
    }
  }

  // merge 4 groups: plain sums (p already normalized to block max)
#pragma unroll
  for (int off = 16; off <= 32; off <<= 1) {
#pragma unroll
    for (int r = 0; r < NREP; ++r)
#pragma unroll
      for (int j = 0; j < 8; ++j) o[r][j] += __shfl_xor(o[r][j], off, 64);
  }

  if (grp == 0) {
#pragma unroll
    for (int r = 0; r < NREP; ++r) {
      float* sp = &smO[wave][r][8 * sl];
      *(float4*)sp       = make_float4(o[r][0], o[r][1], o[r][2], o[r][3]);
      *(float4*)(sp + 4) = make_float4(o[r][4], o[r][5], o[r][6], o[r][7]);
    }
  }
  __syncthreads();

  if (tid < HD) {
    const int d  = tid;
    const int pb = bh * NCHUNK + chunk;
#pragma unroll
    for (int r = 0; r < NREP; ++r) {
      float acc = smO[0][r][d] + smO[1][r][d] + smO[2][r][d] + smO[3][r][d];
      pO[((size_t)pb * NREP + r) * HD + d] = acc;
      if (d == 0) { pM[pb * NREP + r] = Msh[r]; pL[pb * NREP + r] = Lsh[r]; }
    }
  }
}

// ---------------------------------------------------------------------------
// Phase B2: combine NPART partials per (b,h) with exp rescale.
// ---------------------------------------------------------------------------
__global__ __launch_bounds__(256) void attn_combine_k(
    const float* __restrict__ pM, const float* __restrict__ pL,
    const float* __restrict__ pO, float* __restrict__ attn) {
  const int bh  = blockIdx.x;
  const int h   = bh & (NKV - 1);
  const int b   = bh / NKV;
  const int tid = threadIdx.x;
  __shared__ float ml[NREP * NPART], ll[NREP * NPART];
  __shared__ float wgt[NREP * NPART];
  __shared__ float Linv[NREP];

  for (int idx = tid; idx < NREP * NPART; idx += 256) {
    int r = idx / NPART, w = idx - r * NPART;
    ml[idx] = pM[(bh * NPART + w) * NREP + r];
    ll[idx] = pL[(bh * NPART + w) * NREP + r];
  }
  __syncthreads();
  for (int idx = tid; idx < NREP * NPART; idx += 256) {
    int r = idx / NPART;
    float M = -1e30f;
    for (int w = 0; w < NPART; ++w) M = fmaxf(M, ml[r * NPART + w]);
    float e = __expf(ml[idx] - M);
    wgt[idx] = e;
    ll[idx] *= e;
  }
  __syncthreads();
  if (tid < NREP) {
    float L = 0.f;
    for (int w = 0; w < NPART; ++w) L += ll[tid * NPART + w];
    Linv[tid] = 1.f / L;
  }
  __syncthreads();

  for (int oidx = tid; oidx < NREP * HD; oidx += 256) {
    int r = oidx >> 7, d = oidx & 127;
    float acc = 0.f;
    for (int w = 0; w < NPART; ++w)
      acc += wgt[r * NPART + w] * pO[((size_t)(bh * NPART + w) * NREP + r) * HD + d];
    attn[b * DIM + (h * NREP + r) * HD + d] = acc * Linv[r];
  }
}

// ---------------------------------------------------------------------------
// Phase C: output projection GEMV (split-K, 2 cols/thread) + reduce with bias.
// ---------------------------------------------------------------------------
__global__ __launch_bounds__(256) void out_partial_k(
    const float* __restrict__ attn, const float* __restrict__ wo,
    float* __restrict__ part) {
  const int cb = blockIdx.x % 10;
  const int kc = blockIdx.x / 10;
  const int c0 = cb * 512 + threadIdx.x * 2;

  const int i0 = kc * KCH;
  float ax[BS], ay[BS];
#pragma unroll
  for (int b = 0; b < BS; ++b) { ax[b] = 0.f; ay[b] = 0.f; }

  const float* wp = wo + (size_t)i0 * DIM + c0;
  const float* xp = attn + i0;
#pragma unroll 4
  for (int ii = 0; ii < KCH; ++ii) {
    const float2 wv2 = *(const float2*)&wp[(size_t)ii * DIM];
#pragma unroll
    for (int b = 0; b < BS; ++b) {
      const float xb = xp[b * DIM + ii];   // wave-uniform -> scalar load
      ax[b] = fmaf(xb, wv2.x, ax[b]);
      ay[b] = fmaf(xb, wv2.y, ay[b]);
    }
  }
#pragma unroll
  for (int b = 0; b < BS; ++b)
    *(float2*)&part[((size_t)kc * BS + b) * DIM + c0] = make_float2(ax[b], ay[b]);
}

__global__ __launch_bounds__(256) void out_reduce_k(
    const float* __restrict__ part, const float* __restrict__ bo,
    float* __restrict__ out) {
  int g = blockIdx.x * 256 + threadIdx.x;
  if (g >= BS * DIM) return;
  int b = g / DIM, c = g - b * DIM;
  float s = 0.f;
  for (int kc = 0; kc < NKC; ++kc) s += part[((size_t)kc * BS + b) * DIM + c];
  out[g] = s + bo[c];
}

// ---------------------------------------------------------------------------
extern "C" void kernel_launch(void* const* d_in, const int* in_sizes, int n_in,
                              void* d_out, int out_size, void* d_ws, size_t ws_size,
                              hipStream_t stream) {
  const float* x  = (const float*)d_in[0];
  // d_in[1] = start_pos (hardcoded 4095 per problem constants)
  const float* fc = (const float*)d_in[2];
  const float* ck = (const float*)d_in[3];
  const float* cv = (const float*)d_in[4];
  const float* wq = (const float*)d_in[5];
  const float* bq = (const float*)d_in[6];
  const float* wk = (const float*)d_in[7];
  const float* bk = (const float*)d_in[8];
  const float* wv = (const float*)d_in[9];
  const float* bv = (const float*)d_in[10];
  const float* wo = (const float*)d_in[11];
  const float* bo = (const float*)d_in[12];

  float* ws      = (float*)d_ws;
  float* qws     = ws + WS_Q;
  float* kws     = ws + WS_K;
  float* vws     = ws + WS_V;
  float* attn    = ws + WS_ATTN;
  float* scratch = ws + WS_SCRATCH;

  // Phase A: QKV projection
  qkv_partial_k<<<14 * NKC, 256, 0, stream>>>(x, wq, wk, wv, scratch);
  qkv_reduce_k<<<(BS * (ODQKV / 2) + 255) / 256, 256, 0, stream>>>(
      scratch, bq, bk, bv, fc, qws, kws, vws);

  // Phase B: attention (scratch reused for softmax partials)
  float* pM = scratch;
  float* pL = pM + 64 * NPART * NREP;
  float* pO = pL + 64 * NPART * NREP;
  attn_partial_k<<<64 * NCHUNK, 256, 0, stream>>>(ck, cv, qws, kws, vws, pM, pL, pO);
  attn_combine_k<<<64, 256, 0, stream>>>(pM, pL, pO, attn);

  // Phase C: output projection (scratch reused for GEMV partials)
  out_partial_k<<<10 * NKC, 256, 0, stream>>>(attn, wo, scratch);
  out_reduce_k<<<(BS * DIM + 255) / 256, 256, 0, stream>>>(scratch, bo, (float*)d_out);
}